// Round 14
// baseline (22.592 us; speedup 1.0000x reference)
//
#include <hip/hip_runtime.h>
#include <math.h>

// Effective math (cross-attn K/V rows identical per batch element ->
// softmax uniform -> ctx == v; self-attn and QK paths are dead):
//   x   = im_repr @ ca_wv + ca_bv                  [256,768]
//   h   = gelu(x @ fi_w1 + fi_b1)  (exact erf)     [256,256]
//   y   = x + h @ fi_w2 + fi_b2                    [256,768]
//   out = LN(y) * ln_g + ln_b
//
// Round-13: fix kA load imbalance. Was grid(6,64)=384 blocks on 256 CUs
// -> half the CUs run 2 serial blocks (makespan 512 iter-units). Now
// grid(4,64)=256 blocks = exactly 1/CU (makespan 128+192=320 units),
// and kB sums 4 partials instead of 6. kB keeps k-pair-packed bf16 w2.

#define DMODEL 768
#define ENCD   128
#define HID    256
#define KC     4
#define KW     192   // kA k-slice width (DMODEL / KC)

// ws layout (float elements)
#define WS_X   0            // x   [256][768] f32
#define WS_P   196608       // p   [4][256][256] f32
#define WS_W2P 458752       // w2p [128][768] uint (bf16 pairs along k)

__device__ __forceinline__ float gelu_exact(float v) {
    return 0.5f * v * (1.f + erff(v * 0.70710678118654752f));
}
__device__ __forceinline__ unsigned short f2bf(float f) {
    unsigned u = __float_as_uint(f);
    u = (u + 0x7FFFu + ((u >> 16) & 1u)) >> 16;   // RNE
    return (unsigned short)u;
}
__device__ __forceinline__ float bflo(unsigned u) { return __uint_as_float(u << 16); }
__device__ __forceinline__ float bfhi(unsigned u) { return __uint_as_float(u & 0xFFFF0000u); }

// ---- kA: grid(4 kc, 64 rowquads) x 256 thr ----
// prologue: pack w2 -> bf16 pairs (98304 uints over 256 blocks = 384/blk)
// stage1: x[4 rows][kc*192 + c] (192 active thr, 4 row chains)
// stage2: p[kc][4 rows][j=t] over 192-k slice (4 row chains)
__global__ __launch_bounds__(256) void kA(
    const float* __restrict__ im,   // [256,128]
    const float* __restrict__ wv,   // [128,768]
    const float* __restrict__ bv,   // [768]
    const float* __restrict__ w1,   // [768,256]
    const float* __restrict__ w2,   // [256,768]
    float* __restrict__ ws)
{
    __shared__ float im_s[4][ENCD];
    __shared__ float x_s[4][KW];
    const int t  = threadIdx.x;
    const int kc = blockIdx.x;
    const int r0 = blockIdx.y * 4;

    // w2 pack: block id b = by*4+kc in [0,256); covers gid = b*384 .. +384
    {
        const int b = blockIdx.y * KC + kc;
        unsigned* w2p = (unsigned*)(ws + WS_W2P);
        #pragma unroll
        for (int ii = 0; ii < 2; ++ii) {
            const int idx = ii * 128 + (t & 127);       // 0..255 of 384
            const int gid = b * 384 + (t >> 7) * 256 + idx;  // half-split
            if ((t >> 7) * 256 + idx < 384) {
                const int k2 = gid / DMODEL, col = gid % DMODEL;
                w2p[gid] =
                    (unsigned)f2bf(w2[(2 * k2) * DMODEL + col]) |
                    ((unsigned)f2bf(w2[(2 * k2 + 1) * DMODEL + col]) << 16);
            }
        }
    }

    #pragma unroll
    for (int i = t; i < 4 * ENCD; i += 256)
        im_s[i >> 7][i & 127] = im[(r0 + (i >> 7)) * ENCD + (i & 127)];
    __syncthreads();

    // stage 1: t < 192 -> col = kc*192 + t, 4 row chains
    if (t < KW) {
        const int col = kc * KW + t;
        float a0 = 0.f, a1 = 0.f, a2 = 0.f, a3 = 0.f;
        #pragma unroll 16
        for (int e = 0; e < ENCD; ++e) {
            float w = wv[e * DMODEL + col];
            a0 += im_s[0][e] * w;
            a1 += im_s[1][e] * w;
            a2 += im_s[2][e] * w;
            a3 += im_s[3][e] * w;
        }
        float b = bv[col];
        a0 += b; a1 += b; a2 += b; a3 += b;
        ws[WS_X + (r0 + 0) * DMODEL + col] = a0;
        ws[WS_X + (r0 + 1) * DMODEL + col] = a1;
        ws[WS_X + (r0 + 2) * DMODEL + col] = a2;
        ws[WS_X + (r0 + 3) * DMODEL + col] = a3;
        x_s[0][t] = a0;
        x_s[1][t] = a1;
        x_s[2][t] = a2;
        x_s[3][t] = a3;
    }
    __syncthreads();

    // stage 2: j = t, 192-k slice, 4 row chains
    {
        float c0 = 0.f, c1 = 0.f, c2 = 0.f, c3 = 0.f;
        const float* w1c = w1 + kc * KW * HID;
        #pragma unroll 16
        for (int k = 0; k < KW; ++k) {
            float w = w1c[k * HID + t];
            c0 += x_s[0][k] * w;
            c1 += x_s[1][k] * w;
            c2 += x_s[2][k] * w;
            c3 += x_s[3][k] * w;
        }
        float* p = ws + WS_P + kc * (256 * HID);
        p[(r0 + 0) * HID + t] = c0;
        p[(r0 + 1) * HID + t] = c1;
        p[(r0 + 2) * HID + t] = c2;
        p[(r0 + 3) * HID + t] = c3;
    }
}

// ---- kB: 1 row/block, packed-bf16 w2, in-block LayerNorm ----
__global__ __launch_bounds__(768) void kB(
    const float* __restrict__ b1,   // [256]
    const float* __restrict__ b2,   // [768]
    const float* __restrict__ gam,  // [768]
    const float* __restrict__ bet,  // [768]
    const float* __restrict__ ws,
    float* __restrict__ out)        // [256,768]
{
    __shared__ float h_s[HID];
    __shared__ float red[12][2];
    const int t = threadIdx.x, r = blockIdx.x;

    if (t < HID) {
        const float* p = ws + WS_P;
        float v = b1[t];
        #pragma unroll
        for (int kc = 0; kc < KC; ++kc)
            v += p[kc * (256 * HID) + r * HID + t];
        h_s[t] = gelu_exact(v);
    }
    __syncthreads();

    // y[t] = x[r][t] + b2[t] + sum_k2 { h[2k2]*lo + h[2k2+1]*hi }
    const unsigned* w2p = (const unsigned*)(ws + WS_W2P);
    float a0 = 0.f, a1 = 0.f, a2 = 0.f, a3 = 0.f;
    #pragma unroll 8
    for (int k2 = 0; k2 < 128; k2 += 2) {
        unsigned u0 = w2p[k2 * DMODEL + t];
        unsigned u1 = w2p[(k2 + 1) * DMODEL + t];
        a0 += h_s[2 * k2]     * bflo(u0);
        a1 += h_s[2 * k2 + 1] * bfhi(u0);
        a2 += h_s[2 * k2 + 2] * bflo(u1);
        a3 += h_s[2 * k2 + 3] * bfhi(u1);
    }
    const float y = ws[WS_X + r * DMODEL + t] + b2[t] + ((a0 + a1) + (a2 + a3));

    // LayerNorm across 12 waves
    float s = y, q = y * y;
    #pragma unroll
    for (int off = 32; off > 0; off >>= 1) {
        s += __shfl_down(s, off);
        q += __shfl_down(q, off);
    }
    const int lane = t & 63, wave = t >> 6;
    if (lane == 0) { red[wave][0] = s; red[wave][1] = q; }
    __syncthreads();

    float ss = 0.f, qq = 0.f;
    #pragma unroll
    for (int w = 0; w < 12; ++w) { ss += red[w][0]; qq += red[w][1]; }
    const float mu   = ss * (1.f / DMODEL);
    const float rstd = rsqrtf(qq * (1.f / DMODEL) - mu * mu + 1e-12f);

    out[r * DMODEL + t] = (y - mu) * rstd * gam[t] + bet[t];
}

extern "C" void kernel_launch(void* const* d_in, const int* in_sizes, int n_in,
                              void* d_out, int out_size, void* d_ws, size_t ws_size,
                              hipStream_t stream) {
    const float* im  = (const float*)d_in[0];   // im_repr [256,128]
    const float* wv  = (const float*)d_in[13];  // ca_wv   [128,768]
    const float* bv  = (const float*)d_in[14];  // ca_bv   [768]
    const float* w1  = (const float*)d_in[16];  // fi_w1   [768,256]
    const float* b1  = (const float*)d_in[17];  // fi_b1   [256]
    const float* w2  = (const float*)d_in[18];  // fi_w2   [256,768]
    const float* b2  = (const float*)d_in[19];  // fi_b2   [768]
    const float* g   = (const float*)d_in[20];  // ln_g    [768]
    const float* bt  = (const float*)d_in[21];  // ln_b    [768]
    float* out = (float*)d_out;
    float* ws  = (float*)d_ws;

    kA<<<dim3(KC, 64), 256, 0, stream>>>(im, wv, bv, w1, w2, ws);
    kB<<<dim3(256),    768, 0, stream>>>(b1, b2, g, bt, ws, out);
}

// Round 15
// 20.435 us; speedup vs baseline: 1.1056x; 1.1056x over previous
//
#include <hip/hip_runtime.h>
#include <math.h>

// Effective math (cross-attn K/V rows identical per batch element ->
// softmax uniform -> ctx == v; self-attn and QK paths are dead):
//   x   = im_repr @ ca_wv + ca_bv                  [256,768]
//   h   = gelu(x @ fi_w1 + fi_b1)  (exact erf)     [256,256]
//   y   = x + h @ fi_w2 + fi_b2                    [256,768]
//   out = LN(y) * ln_g + ln_b
//
// Round-15: latency-hiding inside the proven 2-launch shape.
//  kA: 512 threads (2 waves/SIMD, was 1). Both stages 2-way k-split with
//      LDS partial combine; same L2 traffic. Packs w2 -> uint4 (8 bf16
//      along k, layout [k8][col], coalesced pack & load).
//  kB: K-loop = 32 x {1 uint4 load, 8 FMAs} (was 128 scalar loads).

#define DMODEL 768
#define ENCD   128
#define HID    256
#define KC     4
#define KW     192   // kA k-slice width (DMODEL / KC)

// ws layout (float elements)
#define WS_X   0            // x   [256][768] f32
#define WS_P   196608       // p   [4][256][256] f32
#define WS_W2Q 458752       // w2q [32][768] uint4 (8 bf16 along k each)

__device__ __forceinline__ float gelu_exact(float v) {
    return 0.5f * v * (1.f + erff(v * 0.70710678118654752f));
}
__device__ __forceinline__ unsigned short f2bf(float f) {
    unsigned u = __float_as_uint(f);
    u = (u + 0x7FFFu + ((u >> 16) & 1u)) >> 16;   // RNE
    return (unsigned short)u;
}
__device__ __forceinline__ float bflo(unsigned u) { return __uint_as_float(u << 16); }
__device__ __forceinline__ float bfhi(unsigned u) { return __uint_as_float(u & 0xFFFF0000u); }
__device__ __forceinline__ unsigned packbf(float a, float b) {
    return (unsigned)f2bf(a) | ((unsigned)f2bf(b) << 16);
}

// ---- kA: grid(4 kc, 64 rowquads) x 512 thr ----
__global__ __launch_bounds__(512) void kA(
    const float* __restrict__ im,   // [256,128]
    const float* __restrict__ wv,   // [128,768]
    const float* __restrict__ bv,   // [768]
    const float* __restrict__ w1,   // [768,256]
    const float* __restrict__ w2,   // [256,768]
    float* __restrict__ ws)
{
    __shared__ float im_s[4][ENCD];
    __shared__ float xp[2][4][KW];    // stage1 e-half partials
    __shared__ float x_s[4][KW];
    __shared__ float php[2][4][HID];  // stage2 k-half partials
    const int t  = threadIdx.x;
    const int kc = blockIdx.x;
    const int r0 = blockIdx.y * 4;

    // ---- w2 quad-pack: 24576 uint4 over 256 blocks = 96/block ----
    if (t < 96) {
        const int qid = (blockIdx.y * KC + kc) * 96 + t;  // [0, 24576)
        const int k8 = qid / DMODEL, col = qid % DMODEL;
        const float* src = w2 + (8 * k8) * DMODEL + col;
        uint4 u;
        u.x = packbf(src[0],          src[DMODEL]);
        u.y = packbf(src[2 * DMODEL], src[3 * DMODEL]);
        u.z = packbf(src[4 * DMODEL], src[5 * DMODEL]);
        u.w = packbf(src[6 * DMODEL], src[7 * DMODEL]);
        ((uint4*)(ws + WS_W2Q))[qid] = u;
    }

    // im rows: 512 threads = exactly 4x128
    im_s[t >> 7][t & 127] = im[(r0 + (t >> 7)) * ENCD + (t & 127)];
    __syncthreads();

    // ---- stage 1: x[4 rows][col], e split 2-way (384 active) ----
    if (t < 2 * KW) {
        const int col = t % KW, eh = t / KW;
        const int colg = kc * KW + col;
        float a0 = 0.f, a1 = 0.f, a2 = 0.f, a3 = 0.f;
        const int e0 = eh * (ENCD / 2);
        #pragma unroll 16
        for (int e = e0; e < e0 + ENCD / 2; ++e) {
            float w = wv[e * DMODEL + colg];
            a0 += im_s[0][e] * w;
            a1 += im_s[1][e] * w;
            a2 += im_s[2][e] * w;
            a3 += im_s[3][e] * w;
        }
        xp[eh][0][col] = a0;
        xp[eh][1][col] = a1;
        xp[eh][2][col] = a2;
        xp[eh][3][col] = a3;
    }
    __syncthreads();
    if (t < KW) {
        const int colg = kc * KW + t;
        const float b = bv[colg];
        #pragma unroll
        for (int r = 0; r < 4; ++r) {
            float v = xp[0][r][t] + xp[1][r][t] + b;
            ws[WS_X + (r0 + r) * DMODEL + colg] = v;
            x_s[r][t] = v;
        }
    }
    __syncthreads();

    // ---- stage 2: p[kc] partial, k split 2-way (512 active) ----
    {
        const int j = t & 255, kh = t >> 8;           // kh in {0,1}
        const int kbase = kh * (KW / 2);              // 96 k each
        float c0 = 0.f, c1 = 0.f, c2 = 0.f, c3 = 0.f;
        const float* w1c = w1 + (kc * KW + kbase) * HID;
        #pragma unroll 16
        for (int k = 0; k < KW / 2; ++k) {
            float w = w1c[k * HID + j];
            c0 += x_s[0][kbase + k] * w;
            c1 += x_s[1][kbase + k] * w;
            c2 += x_s[2][kbase + k] * w;
            c3 += x_s[3][kbase + k] * w;
        }
        php[kh][0][j] = c0;
        php[kh][1][j] = c1;
        php[kh][2][j] = c2;
        php[kh][3][j] = c3;
    }
    __syncthreads();
    if (t < HID) {
        float* p = ws + WS_P + kc * (256 * HID);
        #pragma unroll
        for (int r = 0; r < 4; ++r)
            p[(r0 + r) * HID + t] = php[0][r][t] + php[1][r][t];
    }
}

// ---- kB: 1 row/block, uint4-packed bf16 w2, in-block LayerNorm ----
__global__ __launch_bounds__(768) void kB(
    const float* __restrict__ b1,   // [256]
    const float* __restrict__ b2,   // [768]
    const float* __restrict__ gam,  // [768]
    const float* __restrict__ bet,  // [768]
    const float* __restrict__ ws,
    float* __restrict__ out)        // [256,768]
{
    __shared__ float h_s[HID];
    __shared__ float red[12][2];
    const int t = threadIdx.x, r = blockIdx.x;

    if (t < HID) {
        const float* p = ws + WS_P;
        float v = b1[t];
        #pragma unroll
        for (int kc = 0; kc < KC; ++kc)
            v += p[kc * (256 * HID) + r * HID + t];
        h_s[t] = gelu_exact(v);
    }
    __syncthreads();

    // y[t] = x[r][t] + b2[t] + sum over 32 uint4 (8 bf16 k-values each)
    const uint4* w2q = (const uint4*)(ws + WS_W2Q);
    float a0 = 0.f, a1 = 0.f, a2 = 0.f, a3 = 0.f;
    #pragma unroll 4
    for (int k8 = 0; k8 < 32; ++k8) {
        uint4 u = w2q[k8 * DMODEL + t];
        const int j = 8 * k8;
        a0 += h_s[j + 0] * bflo(u.x); a1 += h_s[j + 1] * bfhi(u.x);
        a2 += h_s[j + 2] * bflo(u.y); a3 += h_s[j + 3] * bfhi(u.y);
        a0 += h_s[j + 4] * bflo(u.z); a1 += h_s[j + 5] * bfhi(u.z);
        a2 += h_s[j + 6] * bflo(u.w); a3 += h_s[j + 7] * bfhi(u.w);
    }
    const float y = ws[WS_X + r * DMODEL + t] + b2[t] + ((a0 + a1) + (a2 + a3));

    // LayerNorm across 12 waves
    float s = y, q = y * y;
    #pragma unroll
    for (int off = 32; off > 0; off >>= 1) {
        s += __shfl_down(s, off);
        q += __shfl_down(q, off);
    }
    const int lane = t & 63, wave = t >> 6;
    if (lane == 0) { red[wave][0] = s; red[wave][1] = q; }
    __syncthreads();

    float ss = 0.f, qq = 0.f;
    #pragma unroll
    for (int w = 0; w < 12; ++w) { ss += red[w][0]; qq += red[w][1]; }
    const float mu   = ss * (1.f / DMODEL);
    const float rstd = rsqrtf(qq * (1.f / DMODEL) - mu * mu + 1e-12f);

    out[r * DMODEL + t] = (y - mu) * rstd * gam[t] + bet[t];
}

extern "C" void kernel_launch(void* const* d_in, const int* in_sizes, int n_in,
                              void* d_out, int out_size, void* d_ws, size_t ws_size,
                              hipStream_t stream) {
    const float* im  = (const float*)d_in[0];   // im_repr [256,128]
    const float* wv  = (const float*)d_in[13];  // ca_wv   [128,768]
    const float* bv  = (const float*)d_in[14];  // ca_bv   [768]
    const float* w1  = (const float*)d_in[16];  // fi_w1   [768,256]
    const float* b1  = (const float*)d_in[17];  // fi_b1   [256]
    const float* w2  = (const float*)d_in[18];  // fi_w2   [256,768]
    const float* b2  = (const float*)d_in[19];  // fi_b2   [768]
    const float* g   = (const float*)d_in[20];  // ln_g    [768]
    const float* bt  = (const float*)d_in[21];  // ln_b    [768]
    float* out = (float*)d_out;
    float* ws  = (float*)d_ws;

    kA<<<dim3(KC, 64), 512, 0, stream>>>(im, wv, bv, w1, w2, ws);
    kB<<<dim3(256),    768, 0, stream>>>(b1, b2, g, bt, ws, out);
}

// Round 16
// 17.595 us; speedup vs baseline: 1.2840x; 1.1614x over previous
//
#include <hip/hip_runtime.h>
#include <math.h>

// Effective math (cross-attn K/V rows identical per batch element ->
// softmax uniform -> ctx == v; self-attn and QK paths are dead):
//   x   = im_repr @ ca_wv + ca_bv                  [256,768]
//   h   = gelu(x @ fi_w1 + fi_b1)  (exact erf)     [256,256]
//   y   = x + h @ fi_w2 + fi_b2                    [256,768]
//   out = LN(y) * ln_g + ln_b
//
// Round-16: float4 weight loads in kA (4-6x fewer load issues), w2-pack
// on otherwise-idle threads, software prefetch in kB.

#define DMODEL 768
#define ENCD   128
#define HID    256
#define KC     4
#define KW     192   // kA k-slice width (DMODEL / KC)

// ws layout (float elements)
#define WS_X   0            // x   [256][768] f32
#define WS_P   196608       // p   [4][256][256] f32
#define WS_W2Q 458752       // w2q [32][768] uint4 (8 bf16 along k each)

__device__ __forceinline__ float gelu_exact(float v) {
    return 0.5f * v * (1.f + erff(v * 0.70710678118654752f));
}
__device__ __forceinline__ unsigned short f2bf(float f) {
    unsigned u = __float_as_uint(f);
    u = (u + 0x7FFFu + ((u >> 16) & 1u)) >> 16;   // RNE
    return (unsigned short)u;
}
__device__ __forceinline__ float bflo(unsigned u) { return __uint_as_float(u << 16); }
__device__ __forceinline__ float bfhi(unsigned u) { return __uint_as_float(u & 0xFFFF0000u); }
__device__ __forceinline__ unsigned packbf(float a, float b) {
    return (unsigned)f2bf(a) | ((unsigned)f2bf(b) << 16);
}

// ---- kA: grid(4 kc, 64 rowquads) x 512 thr ----
__global__ __launch_bounds__(512) void kA(
    const float* __restrict__ im,   // [256,128]
    const float* __restrict__ wv,   // [128,768]
    const float* __restrict__ bv,   // [768]
    const float* __restrict__ w1,   // [768,256]
    const float* __restrict__ w2,   // [256,768]
    float* __restrict__ ws)
{
    __shared__ float im_s[4][ENCD];
    __shared__ float xp[8][4][KW];    // stage1 e-slice partials (24 KB)
    __shared__ float x_s[4][KW];
    __shared__ float php[8][4][HID];  // stage2 k-slice partials (32 KB)
    const int t  = threadIdx.x;
    const int kc = blockIdx.x;
    const int r0 = blockIdx.y * 4;

    // im rows: 512 threads = exactly 4x128
    im_s[t >> 7][t & 127] = im[(r0 + (t >> 7)) * ENCD + (t & 127)];
    __syncthreads();

    // ---- stage 1 (t<384): col-quad q = t%48, e-slice s = t/48 (16 e each)
    //      pack    (384<=t<480): one w2q uint4 each (96/block) ----
    if (t < 384) {
        const int q = t % 48, s = t / 48;
        const int colg = kc * KW + 4 * q;
        const int e0 = s * 16;
        float4 a0 = {0,0,0,0}, a1 = {0,0,0,0}, a2 = {0,0,0,0}, a3 = {0,0,0,0};
        #pragma unroll 8
        for (int e = e0; e < e0 + 16; ++e) {
            const float4 w = *(const float4*)(wv + e * DMODEL + colg);
            const float i0 = im_s[0][e], i1 = im_s[1][e];
            const float i2 = im_s[2][e], i3 = im_s[3][e];
            a0.x += i0 * w.x; a0.y += i0 * w.y; a0.z += i0 * w.z; a0.w += i0 * w.w;
            a1.x += i1 * w.x; a1.y += i1 * w.y; a1.z += i1 * w.z; a1.w += i1 * w.w;
            a2.x += i2 * w.x; a2.y += i2 * w.y; a2.z += i2 * w.z; a2.w += i2 * w.w;
            a3.x += i3 * w.x; a3.y += i3 * w.y; a3.z += i3 * w.z; a3.w += i3 * w.w;
        }
        ((float4*)xp[s][0])[q] = a0;
        ((float4*)xp[s][1])[q] = a1;
        ((float4*)xp[s][2])[q] = a2;
        ((float4*)xp[s][3])[q] = a3;
    } else if (t < 480) {
        const int qid = (blockIdx.y * KC + kc) * 96 + (t - 384);  // [0,24576)
        const int k8 = qid / DMODEL, col = qid % DMODEL;
        const float* src = w2 + (8 * k8) * DMODEL + col;
        uint4 u;
        u.x = packbf(src[0],          src[DMODEL]);
        u.y = packbf(src[2 * DMODEL], src[3 * DMODEL]);
        u.z = packbf(src[4 * DMODEL], src[5 * DMODEL]);
        u.w = packbf(src[6 * DMODEL], src[7 * DMODEL]);
        ((uint4*)(ws + WS_W2Q))[qid] = u;
    }
    __syncthreads();

    // combine stage-1 partials
    if (t < KW) {
        const int colg = kc * KW + t;
        const float b = bv[colg];
        #pragma unroll
        for (int r = 0; r < 4; ++r) {
            float v = b;
            #pragma unroll
            for (int s = 0; s < 8; ++s) v += xp[s][r][t];
            ws[WS_X + (r0 + r) * DMODEL + colg] = v;
            x_s[r][t] = v;
        }
    }
    __syncthreads();

    // ---- stage 2: j-quad jq = t&63, k-slice ks = t>>6 (24 k each) ----
    {
        const int jq = t & 63, ks = t >> 6;
        const int k0 = ks * 24;
        float4 a0 = {0,0,0,0}, a1 = {0,0,0,0}, a2 = {0,0,0,0}, a3 = {0,0,0,0};
        const float* w1c = w1 + (size_t)kc * KW * HID;
        #pragma unroll 8
        for (int kk = 0; kk < 24; ++kk) {
            const int k = k0 + kk;
            const float4 w = *(const float4*)(w1c + k * HID + 4 * jq);
            const float x0 = x_s[0][k], x1 = x_s[1][k];
            const float x2 = x_s[2][k], x3 = x_s[3][k];
            a0.x += x0 * w.x; a0.y += x0 * w.y; a0.z += x0 * w.z; a0.w += x0 * w.w;
            a1.x += x1 * w.x; a1.y += x1 * w.y; a1.z += x1 * w.z; a1.w += x1 * w.w;
            a2.x += x2 * w.x; a2.y += x2 * w.y; a2.z += x2 * w.z; a2.w += x2 * w.w;
            a3.x += x3 * w.x; a3.y += x3 * w.y; a3.z += x3 * w.z; a3.w += x3 * w.w;
        }
        ((float4*)php[ks][0])[jq] = a0;
        ((float4*)php[ks][1])[jq] = a1;
        ((float4*)php[ks][2])[jq] = a2;
        ((float4*)php[ks][3])[jq] = a3;
    }
    __syncthreads();

    if (t < HID) {
        float* p = ws + WS_P + kc * (256 * HID);
        #pragma unroll
        for (int r = 0; r < 4; ++r) {
            float v = 0.f;
            #pragma unroll
            for (int s = 0; s < 8; ++s) v += php[s][r][t];
            p[(r0 + r) * HID + t] = v;
        }
    }
}

// ---- kB: 1 row/block, uint4 bf16 w2 with prefetch, in-block LN ----
__global__ __launch_bounds__(768) void kB(
    const float* __restrict__ b1,   // [256]
    const float* __restrict__ b2,   // [768]
    const float* __restrict__ gam,  // [768]
    const float* __restrict__ bet,  // [768]
    const float* __restrict__ ws,
    float* __restrict__ out)        // [256,768]
{
    __shared__ float h_s[HID];
    __shared__ float red[12][2];
    const int t = threadIdx.x, r = blockIdx.x;

    // prefetch (independent of h): first 8 w2q quads + x + b2
    const uint4* w2q = (const uint4*)(ws + WS_W2Q);
    uint4 u0 = w2q[0 * DMODEL + t];
    uint4 u1 = w2q[1 * DMODEL + t];
    uint4 u2 = w2q[2 * DMODEL + t];
    uint4 u3 = w2q[3 * DMODEL + t];
    uint4 u4 = w2q[4 * DMODEL + t];
    uint4 u5 = w2q[5 * DMODEL + t];
    uint4 u6 = w2q[6 * DMODEL + t];
    uint4 u7 = w2q[7 * DMODEL + t];
    const float xv  = ws[WS_X + r * DMODEL + t];
    const float b2v = b2[t];

    if (t < HID) {
        const float* p = ws + WS_P;
        float v = b1[t];
        #pragma unroll
        for (int kc = 0; kc < KC; ++kc)
            v += p[kc * (256 * HID) + r * HID + t];
        h_s[t] = gelu_exact(v);
    }
    __syncthreads();

    float a0 = 0.f, a1 = 0.f, a2 = 0.f, a3 = 0.f;
    #define PROC(U, J)                                                  \
        a0 += h_s[(J) + 0] * bflo(U.x); a1 += h_s[(J) + 1] * bfhi(U.x); \
        a2 += h_s[(J) + 2] * bflo(U.y); a3 += h_s[(J) + 3] * bfhi(U.y); \
        a0 += h_s[(J) + 4] * bflo(U.z); a1 += h_s[(J) + 5] * bfhi(U.z); \
        a2 += h_s[(J) + 6] * bflo(U.w); a3 += h_s[(J) + 7] * bfhi(U.w);
    PROC(u0, 0)  PROC(u1, 8)  PROC(u2, 16) PROC(u3, 24)
    PROC(u4, 32) PROC(u5, 40) PROC(u6, 48) PROC(u7, 56)
    #pragma unroll 4
    for (int k8 = 8; k8 < 32; ++k8) {
        uint4 u = w2q[k8 * DMODEL + t];
        const int j = 8 * k8;
        PROC(u, j)
    }
    #undef PROC
    const float y = xv + b2v + ((a0 + a1) + (a2 + a3));

    // LayerNorm across 12 waves
    float s = y, q = y * y;
    #pragma unroll
    for (int off = 32; off > 0; off >>= 1) {
        s += __shfl_down(s, off);
        q += __shfl_down(q, off);
    }
    const int lane = t & 63, wave = t >> 6;
    if (lane == 0) { red[wave][0] = s; red[wave][1] = q; }
    __syncthreads();

    float ss = 0.f, qq = 0.f;
    #pragma unroll
    for (int w = 0; w < 12; ++w) { ss += red[w][0]; qq += red[w][1]; }
    const float mu   = ss * (1.f / DMODEL);
    const float rstd = rsqrtf(qq * (1.f / DMODEL) - mu * mu + 1e-12f);

    out[r * DMODEL + t] = (y - mu) * rstd * gam[t] + bet[t];
}

extern "C" void kernel_launch(void* const* d_in, const int* in_sizes, int n_in,
                              void* d_out, int out_size, void* d_ws, size_t ws_size,
                              hipStream_t stream) {
    const float* im  = (const float*)d_in[0];   // im_repr [256,128]
    const float* wv  = (const float*)d_in[13];  // ca_wv   [128,768]
    const float* bv  = (const float*)d_in[14];  // ca_bv   [768]
    const float* w1  = (const float*)d_in[16];  // fi_w1   [768,256]
    const float* b1  = (const float*)d_in[17];  // fi_b1   [256]
    const float* w2  = (const float*)d_in[18];  // fi_w2   [256,768]
    const float* b2  = (const float*)d_in[19];  // fi_b2   [768]
    const float* g   = (const float*)d_in[20];  // ln_g    [768]
    const float* bt  = (const float*)d_in[21];  // ln_b    [768]
    float* out = (float*)d_out;
    float* ws  = (float*)d_ws;

    kA<<<dim3(KC, 64), 512, 0, stream>>>(im, wv, bv, w1, w2, ws);
    kB<<<dim3(256),    768, 0, stream>>>(b1, b2, g, bt, ws, out);
}